// Round 2
// baseline (22397.449 us; speedup 1.0000x reference)
//
#include <hip/hip_runtime.h>
#include <hip/hip_fp16.h>
#include <stdint.h>

#define TIME_STEPS 4096
#define DIM        2048
#define NWG        128
#define NTH        256
#define NB         8            // activation ring depth (power of 2)
#define PITCH      132          // 128 + 4 floats pad: kills 16-way LDS conflict

typedef uint32_t u32x4 __attribute__((ext_vector_type(4)));

// d_ws layout:
//   [0, NB*DIM*4)         activation ring, u32 = (gen_tag16 << 16) | fp16(act)
//   [NB*DIM*4, +NWG*4)    progress[wg] = last staged gen

__global__ __launch_bounds__(NTH, 1) void ctrnn_kernel(
    const float* __restrict__ x,        // [TIME, DIM]
    const float* __restrict__ W,        // [DIM, DIM] row-major
    const float* __restrict__ bias,     // [DIM]
    const float* __restrict__ initial,  // [DIM]
    float* __restrict__ out,            // [TIME, DIM]
    uint32_t* __restrict__ actbuf,
    uint32_t* __restrict__ progress)
{
  const int wg  = blockIdx.x;
  const int tid = threadIdx.x;
  const int s   = tid & 15;     // k-slice (0..15), 128 k each
  const int r   = tid >> 4;     // row within WG (0..15)
  const int j   = wg * 16 + r;  // global row for the dot product

  __shared__ float act_lds[2][16 * PITCH];
  __shared__ float p_buf[2][16];

  // W[j][s*128 .. +128) in registers (compiler may park in AGPRs — fine).
  float4 wreg[32];
  {
    const float4* wrow = reinterpret_cast<const float4*>(W + (size_t)j * DIM + s * 128);
    #pragma unroll
    for (int i = 0; i < 32; ++i) wreg[i] = wrow[i];
  }

  // State lives in wave 0, lanes 0..15 (one coalesced 64B publish per WG).
  const bool state_lane = (tid < 16);
  const int  js = wg * 16 + tid;     // state row for state lanes
  float v = 0.f, bj = 0.f, xv = 0.f;
  if (state_lane) {
    v  = initial[js];
    bj = bias[js];
    xv = x[js];
    out[js] = v;
    const float a0 = 1.0f / (1.0f + __expf(-(v + bj)));
    __half h0 = __float2half_rn(a0);
    unsigned short us0; __builtin_memcpy(&us0, &h0, 2);
    const uint32_t e0 = (1u << 16) | us0;
    __hip_atomic_store(&actbuf[js], e0, __ATOMIC_RELAXED, __HIP_MEMORY_SCOPE_AGENT);
  }

  unsigned prog_seen = 0;

  for (int t = 0; t < TIME_STEPS - 1; ++t) {
    const int b = t & 1;

    // Early x prefetch (used at end of step; hidden under poll+dot).
    float xn = 0.f;
    if (state_lane) xn = x[(size_t)(t + 1) * DIM + js];

    // ---- poll slot t&7 (8 entries/thread as two 16B quads), stage to LDS ----
    const uint32_t* src = actbuf + (size_t)(t & (NB - 1)) * DIM + tid * 8;
    const uint32_t needtag = (uint32_t)(t + 1);
    float* dst = &act_lds[b][(tid >> 4) * PITCH + (tid & 15) * 8];

    u32x4 q0, q1;
    asm volatile("global_load_dwordx4 %0, %2, off sc0 sc1\n\t"
                 "global_load_dwordx4 %1, %3, off sc0 sc1\n\t"
                 "s_waitcnt vmcnt(0)"
                 : "=&v"(q0), "=&v"(q1)
                 : "v"(src), "v"(src + 4)
                 : "memory");
    uint32_t pend = 0xFFu;
    for (;;) {
      #pragma unroll
      for (int i = 0; i < 4; ++i) {
        if ((pend >> i) & 1u) {
          const uint32_t e = q0[i];
          if ((e >> 16) == needtag) {
            unsigned short us = (unsigned short)(e & 0xFFFFu);
            __half h; __builtin_memcpy(&h, &us, 2);
            dst[i] = __half2float(h);
            pend &= ~(1u << i);
          }
        }
      }
      #pragma unroll
      for (int i = 0; i < 4; ++i) {
        if ((pend >> (4 + i)) & 1u) {
          const uint32_t e = q1[i];
          if ((e >> 16) == needtag) {
            unsigned short us = (unsigned short)(e & 0xFFFFu);
            __half h; __builtin_memcpy(&h, &us, 2);
            dst[4 + i] = __half2float(h);
            pend &= ~(1u << (4 + i));
          }
        }
      }
      if (!pend) break;
      asm volatile("global_load_dwordx4 %0, %2, off sc0 sc1\n\t"
                   "global_load_dwordx4 %1, %3, off sc0 sc1\n\t"
                   "s_waitcnt vmcnt(0)"
                   : "=&v"(q0), "=&v"(q1)
                   : "v"(src), "v"(src + 4)
                   : "memory");
    }

    __syncthreads();  // act_lds[b] fully staged; p_buf[b] free (last read t-2)

    if (tid == 0)
      __hip_atomic_store(&progress[wg], (unsigned)(t + 1),
                         __ATOMIC_RELAXED, __HIP_MEMORY_SCOPE_AGENT);

    // ---- WAR-gate loads issued here, evaluated after the dot (latency hidden) ----
    const unsigned need = (t >= NB - 1) ? (unsigned)(t + 1 - (NB - 1)) : 0u;
    const bool gate = (need > prog_seen);
    unsigned pa = 0xFFFFFFFFu, pb = 0xFFFFFFFFu;
    if (gate) {
      const int lane = tid & 63;
      pa = __hip_atomic_load(&progress[lane],      __ATOMIC_RELAXED, __HIP_MEMORY_SCOPE_AGENT);
      pb = __hip_atomic_load(&progress[lane + 64], __ATOMIC_RELAXED, __HIP_MEMORY_SCOPE_AGENT);
    }

    // ---- partial dot over slice s ----
    float4 acc = {0.f, 0.f, 0.f, 0.f};
    const float4* ap = reinterpret_cast<const float4*>(&act_lds[b][s * PITCH]);
    #pragma unroll
    for (int i = 0; i < 32; ++i) {
      const float4 a4 = ap[i];
      acc.x = fmaf(wreg[i].x, a4.x, acc.x);
      acc.y = fmaf(wreg[i].y, a4.y, acc.y);
      acc.z = fmaf(wreg[i].z, a4.z, acc.z);
      acc.w = fmaf(wreg[i].w, a4.w, acc.w);
    }
    float p = (acc.x + acc.y) + (acc.z + acc.w);
    p += __shfl_xor(p, 1, 64);
    p += __shfl_xor(p, 2, 64);
    p += __shfl_xor(p, 4, 64);
    p += __shfl_xor(p, 8, 64);
    if (s == 0) p_buf[b][r] = p;

    // ---- evaluate WAR gate (rarely spins: WGs are lockstep ±1) ----
    if (gate) {
      unsigned mn = pa < pb ? pa : pb;
      if      (__all(mn >= (unsigned)(t + 1))) prog_seen = (unsigned)(t + 1);
      else if (__all(mn >= need))              prog_seen = need;
      else {
        const int lane = tid & 63;
        for (;;) {
          pa = __hip_atomic_load(&progress[lane],      __ATOMIC_RELAXED, __HIP_MEMORY_SCOPE_AGENT);
          pb = __hip_atomic_load(&progress[lane + 64], __ATOMIC_RELAXED, __HIP_MEMORY_SCOPE_AGENT);
          mn = pa < pb ? pa : pb;
          if (__all(mn >= (unsigned)(t + 1))) { prog_seen = (unsigned)(t + 1); break; }
          if (__all(mn >= need))              { prog_seen = need;              break; }
        }
      }
    }

    __syncthreads();  // p_buf[b] visible to wave 0; gate satisfied by everyone

    // ---- state update + single coalesced 64B publish (wave 0 lanes 0..15) ----
    if (state_lane) {
      const float pr = p_buf[b][tid];
      v  = 0.9f * v + 0.1f * (pr + xv);
      xv = xn;
      out[(size_t)(t + 1) * DIM + js] = v;
      const float a = 1.0f / (1.0f + __expf(-(v + bj)));
      __half h = __float2half_rn(a);
      unsigned short us; __builtin_memcpy(&us, &h, 2);
      const uint32_t e = ((uint32_t)(t + 2) << 16) | us;
      __hip_atomic_store(&actbuf[(size_t)((t + 1) & (NB - 1)) * DIM + js], e,
                         __ATOMIC_RELAXED, __HIP_MEMORY_SCOPE_AGENT);
    }
    // Non-state waves fall straight into polling slot t+1.
  }
}

extern "C" void kernel_launch(void* const* d_in, const int* in_sizes, int n_in,
                              void* d_out, int out_size, void* d_ws, size_t ws_size,
                              hipStream_t stream) {
  const float* x       = (const float*)d_in[0];
  const float* W       = (const float*)d_in[1];
  const float* bias    = (const float*)d_in[2];
  const float* initial = (const float*)d_in[3];
  float* out           = (float*)d_out;

  uint32_t* actbuf   = (uint32_t*)d_ws;
  uint32_t* progress = (uint32_t*)((char*)d_ws + (size_t)NB * DIM * 4);

  // Tags are generation counters — must start at 0 every call.
  hipMemsetAsync(d_ws, 0, (size_t)NB * DIM * 4 + NWG * 4, stream);

  void* args[] = { (void*)&x, (void*)&W, (void*)&bias, (void*)&initial,
                   (void*)&out, (void*)&actbuf, (void*)&progress };
  hipLaunchCooperativeKernel((void*)ctrnn_kernel, dim3(NWG), dim3(NTH),
                             args, 0, stream);
}